// Round 2
// baseline (353.754 us; speedup 1.0000x reference)
//
#include <hip/hip_runtime.h>

#define EDIM 10
#define TDIM 50
#define BATCH 65536
#define CWN 640   // 630 used + pad

// Collapsed-weight global (written by collapse_weights, read via SMEM by augru_main):
//   [0..9]    bias_r   [10..19] bias_z   [20..29] bias_h     (bias_g = bi_g @ Ws_g + bs_g)
//   [30+g*100 + k*10 + j]  A_g[k][j] = (Wi_g @ Ws_g)[k][j]   g: 0=r,1=z,2=h
//   [330+g*100 + k*10 + j] B_g[k][j] = (Wh_g @ Ws_g)[k][j]
__device__ float g_cw[CWN];

// constant address space -> s_load (weights are wave-uniform in the
// row-per-lane layout, so they ride the free scalar operand of v_fma)
typedef const __attribute__((address_space(4))) float cfloat;

__device__ __forceinline__ float fast_sigmoid(float x) {
    float e = __expf(-x);
    return __builtin_amdgcn_rcpf(1.0f + e);
}
__device__ __forceinline__ float fast_tanh(float x) {
    float e = __expf(2.0f * x);
    return 1.0f - 2.0f * __builtin_amdgcn_rcpf(e + 1.0f);
}

__global__ void collapse_weights(
    const float* __restrict__ Wi_r, const float* __restrict__ bi_r,
    const float* __restrict__ Wh_r, const float* __restrict__ Ws_r, const float* __restrict__ bs_r,
    const float* __restrict__ Wi_z, const float* __restrict__ bi_z,
    const float* __restrict__ Wh_z, const float* __restrict__ Ws_z, const float* __restrict__ bs_z,
    const float* __restrict__ Wi_h, const float* __restrict__ bi_h,
    const float* __restrict__ Wh_h, const float* __restrict__ Wt_h, const float* __restrict__ bt_h)
{
    for (int s = threadIdx.x; s < 630; s += 256) {
        int g, kind, k, e;
        if (s < 30)       { kind = 0; g = s / 10;      k = 0;                e = s % 10; }
        else if (s < 330) { kind = 1; int q = s - 30;  g = q / 100; k = (q % 100) / 10; e = q % 10; }
        else              { kind = 2; int q = s - 330; g = q / 100; k = (q % 100) / 10; e = q % 10; }
        const float* Wi = (g == 0) ? Wi_r : (g == 1) ? Wi_z : Wi_h;
        const float* Wh = (g == 0) ? Wh_r : (g == 1) ? Wh_z : Wh_h;
        const float* Ws = (g == 0) ? Ws_r : (g == 1) ? Ws_z : Wt_h;
        const float* bi = (g == 0) ? bi_r : (g == 1) ? bi_z : bi_h;
        const float* bs = (g == 0) ? bs_r : (g == 1) ? bs_z : bt_h;
        float v = 0.0f;
        if (kind == 0) {
            v = bs[e];
            #pragma unroll
            for (int j = 0; j < 10; j++) v += bi[j] * Ws[j * 10 + e];
        } else {
            const float* M = (kind == 1) ? Wi : Wh;
            #pragma unroll
            for (int j = 0; j < 10; j++) v += M[k * 10 + j] * Ws[j * 10 + e];
        }
        g_cw[s] = v;
    }
}

__global__ __launch_bounds__(256, 1) void augru_main(
    const float* __restrict__ x_all, const float* __restrict__ a_all,
    const float* __restrict__ h0,
    float* __restrict__ out)
{
    const int row = blockIdx.x * 256 + threadIdx.x;   // one FULL row per lane

    cfloat* cw = (cfloat*)(uintptr_t)(const float*)g_cw;

    const float2* xp = (const float2*)(x_all + (size_t)row * (TDIM * EDIM));
    const float2* ap = (const float2*)(a_all + (size_t)row * (TDIM * EDIM));

    float h[10];
    #pragma unroll
    for (int j = 0; j < 10; j++) h[j] = h0[j];   // uniform -> scalar loads

    float xc[10], ac[10];
    #pragma unroll
    for (int i = 0; i < 5; i++) {
        float2 v = xp[i]; xc[2 * i] = v.x; xc[2 * i + 1] = v.y;
        float2 u = ap[i]; ac[2 * i] = u.x; ac[2 * i + 1] = u.y;
    }

    // SGPR-laundered offset: makes every weight address loop-variant so LICM
    // cannot hoist the 630 s_loads out of the t-loop (no SGPR budget for that
    // -> would scalar-spill). Same rationale as the proven wofs/FENCEW tricks.
    int sofs = 0;

    #pragma unroll 1
    for (int t = 0; t < TDIM; t++) {
        asm volatile("" : "+s"(sofs));
        cfloat* w = cw + sofs;

        // branchless 1-step-lookahead prefetch (clamped); ~1500cy of compute
        // below covers the HBM latency.
        int tn = (t < TDIM - 1) ? (t + 1) : t;
        float xn[10], an[10];
        #pragma unroll
        for (int i = 0; i < 5; i++) {
            float2 v = xp[tn * 5 + i]; xn[2 * i] = v.x; xn[2 * i + 1] = v.y;
            float2 u = ap[tn * 5 + i]; an[2 * i] = u.x; an[2 * i + 1] = u.y;
        }

        float ur[10], uz[10], uh[10];
        #pragma unroll
        for (int j = 0; j < 10; j++) {
            ur[j] = w[j]; uz[j] = w[10 + j]; uh[j] = w[20 + j];
        }

        #pragma unroll
        for (int k = 0; k < 10; k++) {          // x @ A_r
            float xk = xc[k];
            #pragma unroll
            for (int j = 0; j < 10; j++) ur[j] = fmaf(xk, w[30 + k * 10 + j], ur[j]);
        }
        #pragma unroll
        for (int k = 0; k < 10; k++) {          // x @ A_z
            float xk = xc[k];
            #pragma unroll
            for (int j = 0; j < 10; j++) uz[j] = fmaf(xk, w[130 + k * 10 + j], uz[j]);
        }
        #pragma unroll
        for (int k = 0; k < 10; k++) {          // h @ B_r
            float hk = h[k];
            #pragma unroll
            for (int j = 0; j < 10; j++) ur[j] = fmaf(hk, w[330 + k * 10 + j], ur[j]);
        }
        #pragma unroll
        for (int k = 0; k < 10; k++) {          // h @ B_z
            float hk = h[k];
            #pragma unroll
            for (int j = 0; j < 10; j++) uz[j] = fmaf(hk, w[430 + k * 10 + j], uz[j]);
        }
        // x @ A_h before the z-sigmoids are consumed: independent FMA stream
        // that covers the transcendental latency.
        #pragma unroll
        for (int k = 0; k < 10; k++) {
            float xk = xc[k];
            #pragma unroll
            for (int j = 0; j < 10; j++) uh[j] = fmaf(xk, w[230 + k * 10 + j], uh[j]);
        }

        float hz[10];
        #pragma unroll
        for (int j = 0; j < 10; j++) hz[j] = h[j] * fast_sigmoid(uz[j]);

        #pragma unroll
        for (int k = 0; k < 10; k++) {          // (h*z) @ B_h
            float hk = hz[k];
            #pragma unroll
            for (int j = 0; j < 10; j++) uh[j] = fmaf(hk, w[530 + k * 10 + j], uh[j]);
        }

        #pragma unroll
        for (int j = 0; j < 10; j++) {
            float r  = fast_sigmoid(ur[j]);
            float hc = fast_tanh(uh[j]);
            float Ra = ac[j] * r;
            h[j] = fmaf(Ra, hc - h[j], h[j]);
        }

        #pragma unroll
        for (int j = 0; j < 10; j++) { xc[j] = xn[j]; ac[j] = an[j]; }
    }

    // lane L writes bytes [40L, 40L+40) -> wave store fully contiguous
    float2* orow = (float2*)(out + (size_t)row * EDIM);
    #pragma unroll
    for (int i = 0; i < 5; i++) orow[i] = make_float2(h[2 * i], h[2 * i + 1]);
}

extern "C" void kernel_launch(void* const* d_in, const int* in_sizes, int n_in,
                              void* d_out, int out_size, void* d_ws, size_t ws_size,
                              hipStream_t stream) {
    collapse_weights<<<1, 256, 0, stream>>>(
        (const float*)d_in[3],  (const float*)d_in[4],  (const float*)d_in[5],
        (const float*)d_in[6],  (const float*)d_in[7],
        (const float*)d_in[8],  (const float*)d_in[9],  (const float*)d_in[10],
        (const float*)d_in[11], (const float*)d_in[12],
        (const float*)d_in[13], (const float*)d_in[14], (const float*)d_in[15],
        (const float*)d_in[16], (const float*)d_in[17]);
    augru_main<<<BATCH / 256, 256, 0, stream>>>(
        (const float*)d_in[0], (const float*)d_in[1], (const float*)d_in[2],
        (float*)d_out);
}